// Round 1
// baseline (14525.793 us; speedup 1.0000x reference)
//
#include <hip/hip_runtime.h>

#define N_NODES 50000
#define N_EDGES 800000
// feats: 512 -> 512 -> 512 -> 256

// ---------------- degree / norm ----------------
__global__ void deg_kernel(const int* __restrict__ src, const int* __restrict__ dst,
                           float* __restrict__ outdeg, float* __restrict__ indeg) {
    int i = blockIdx.x * blockDim.x + threadIdx.x;
    if (i < N_EDGES) {
        atomicAdd(&outdeg[src[i]], 1.0f);
        atomicAdd(&indeg[dst[i]], 1.0f);
    }
}

__global__ void norm_kernel(float* __restrict__ deg, int n) {
    int i = blockIdx.x * blockDim.x + threadIdx.x;
    if (i < n) deg[i] = rsqrtf(fmaxf(deg[i], 1.0f));
}

// ---------------- fp32 tiled GEMM, C = (A @ B) * rowscale[row] ----------------
// A: [M,K] row-major, B: [K,N] row-major, C: [M,N]. Tile 64x64, BK=16, 256 thr, 4x4/thread.
__global__ __launch_bounds__(256) void gemm_rowscale(
    const float* __restrict__ A, const float* __restrict__ B,
    float* __restrict__ C, const float* __restrict__ rowscale,
    int M, int N, int K)
{
    __shared__ float sA[16][65];   // [k][row], +1 pad kills store conflicts
    __shared__ float sB[16][64];   // [k][col]

    const int tid = threadIdx.x;
    const int tx = tid & 15;       // col group
    const int ty = tid >> 4;       // row group
    const int rowBase = blockIdx.x * 64;
    const int colBase = blockIdx.y * 64;

    // A staging: each thread loads float4 A[rowBase+lar][k0+lak .. +3]
    const int lar = tid >> 2;          // 0..63
    const int lak = (tid & 3) << 2;    // 0,4,8,12
    // B staging: each thread loads float4 B[k0+lbk][colBase+lbc .. +3]
    const int lbk = tid >> 4;          // 0..15
    const int lbc = (tid & 15) << 2;   // 0..60

    const int arow = rowBase + lar;
    const bool aok = (arow < M);

    float acc[4][4];
#pragma unroll
    for (int i = 0; i < 4; ++i)
#pragma unroll
        for (int j = 0; j < 4; ++j) acc[i][j] = 0.0f;

    for (int k0 = 0; k0 < K; k0 += 16) {
        float4 av = make_float4(0.f, 0.f, 0.f, 0.f);
        if (aok) av = *(const float4*)(A + (size_t)arow * K + k0 + lak);
        float4 bv = *(const float4*)(B + (size_t)(k0 + lbk) * N + colBase + lbc);

        sA[lak + 0][lar] = av.x;
        sA[lak + 1][lar] = av.y;
        sA[lak + 2][lar] = av.z;
        sA[lak + 3][lar] = av.w;
        *(float4*)&sB[lbk][lbc] = bv;
        __syncthreads();

#pragma unroll
        for (int k = 0; k < 16; ++k) {
            float a0 = sA[k][ty * 4 + 0];
            float a1 = sA[k][ty * 4 + 1];
            float a2 = sA[k][ty * 4 + 2];
            float a3 = sA[k][ty * 4 + 3];
            float4 b = *(float4*)&sB[k][tx * 4];
            acc[0][0] += a0 * b.x; acc[0][1] += a0 * b.y; acc[0][2] += a0 * b.z; acc[0][3] += a0 * b.w;
            acc[1][0] += a1 * b.x; acc[1][1] += a1 * b.y; acc[1][2] += a1 * b.z; acc[1][3] += a1 * b.w;
            acc[2][0] += a2 * b.x; acc[2][1] += a2 * b.y; acc[2][2] += a2 * b.z; acc[2][3] += a2 * b.w;
            acc[3][0] += a3 * b.x; acc[3][1] += a3 * b.y; acc[3][2] += a3 * b.z; acc[3][3] += a3 * b.w;
        }
        __syncthreads();
    }

#pragma unroll
    for (int i = 0; i < 4; ++i) {
        int r = rowBase + ty * 4 + i;
        if (r < M) {
            float s = rowscale[r];
            float4 o;
            o.x = acc[i][0] * s; o.y = acc[i][1] * s;
            o.z = acc[i][2] * s; o.w = acc[i][3] * s;
            *(float4*)(C + (size_t)r * N + colBase + tx * 4) = o;
        }
    }
}

// ---------------- edge scatter: AGG[dst] += H[src] ----------------
template<int F4, int EPB>
__global__ __launch_bounds__(F4 * EPB) void scatter_add(
    const float4* __restrict__ H4, const int* __restrict__ src,
    const int* __restrict__ dst, float* __restrict__ AGG, int E)
{
    int e = blockIdx.x * EPB + threadIdx.y;
    if (e >= E) return;
    int s = src[e];
    int d = dst[e];
    float4 v = H4[(size_t)s * F4 + threadIdx.x];
    float* p = AGG + ((size_t)d * F4 + threadIdx.x) * 4;
    atomicAdd(p + 0, v.x);
    atomicAdd(p + 1, v.y);
    atomicAdd(p + 2, v.z);
    atomicAdd(p + 3, v.w);
}

// ---------------- finalize: X = [relu](X * in_norm[row] + bias[col]) ----------------
__global__ void finalize_kernel(float* __restrict__ X, const float* __restrict__ inn,
                                const float* __restrict__ bias, int shift /*log2(F/4)*/,
                                int relu, long total4)
{
    long i = (long)blockIdx.x * blockDim.x + threadIdx.x;
    if (i >= total4) return;
    int row = (int)(i >> shift);
    long mask = (1L << shift) - 1;
    int c4 = (int)(i & mask);
    float s = inn[row];
    float4 b = ((const float4*)bias)[c4];
    float4 v = ((float4*)X)[i];
    float4 r;
    r.x = v.x * s + b.x;
    r.y = v.y * s + b.y;
    r.z = v.z * s + b.z;
    r.w = v.w * s + b.w;
    if (relu) {
        r.x = fmaxf(r.x, 0.f); r.y = fmaxf(r.y, 0.f);
        r.z = fmaxf(r.z, 0.f); r.w = fmaxf(r.w, 0.f);
    }
    ((float4*)X)[i] = r;
}

extern "C" void kernel_launch(void* const* d_in, const int* in_sizes, int n_in,
                              void* d_out, int out_size, void* d_ws, size_t ws_size,
                              hipStream_t stream) {
    const float* feat = (const float*)d_in[0];
    const int*   src  = (const int*)d_in[1];
    const int*   dst  = (const int*)d_in[2];
    const float* W0   = (const float*)d_in[3];
    const float* b0   = (const float*)d_in[4];
    const float* W1   = (const float*)d_in[5];
    const float* b1   = (const float*)d_in[6];
    const float* W2   = (const float*)d_in[7];
    const float* b2   = (const float*)d_in[8];
    float* out = (float*)d_out;

    float* norms = (float*)d_ws;                 // [2*N_NODES]: out_norm | in_norm
    float* outn  = norms;
    float* inn   = norms + N_NODES;
    float* H     = norms + 2 * N_NODES;          // [N_NODES, 512]
    float* AGG   = H + (size_t)N_NODES * 512;    // [N_NODES, 512]

    // degrees -> norms
    hipMemsetAsync(norms, 0, 2 * N_NODES * sizeof(float), stream);
    deg_kernel<<<(N_EDGES + 255) / 256, 256, 0, stream>>>(src, dst, outn, inn);
    norm_kernel<<<(2 * N_NODES + 255) / 256, 256, 0, stream>>>(norms, 2 * N_NODES);

    dim3 g512((N_NODES + 63) / 64, 512 / 64);
    dim3 g256((N_NODES + 63) / 64, 256 / 64);
    long total4_512 = (long)N_NODES * 128;
    long total4_256 = (long)N_NODES * 64;

    // ---- layer 0 ----
    gemm_rowscale<<<g512, 256, 0, stream>>>(feat, W0, H, outn, N_NODES, 512, 512);
    hipMemsetAsync(AGG, 0, (size_t)N_NODES * 512 * sizeof(float), stream);
    scatter_add<128, 2><<<dim3((N_EDGES + 1) / 2), dim3(128, 2), 0, stream>>>(
        (const float4*)H, src, dst, AGG, N_EDGES);
    finalize_kernel<<<(int)((total4_512 + 255) / 256), 256, 0, stream>>>(
        AGG, inn, b0, 7, 1, total4_512);

    // ---- layer 1 ----
    gemm_rowscale<<<g512, 256, 0, stream>>>(AGG, W1, H, outn, N_NODES, 512, 512);
    hipMemsetAsync(AGG, 0, (size_t)N_NODES * 512 * sizeof(float), stream);
    scatter_add<128, 2><<<dim3((N_EDGES + 1) / 2), dim3(128, 2), 0, stream>>>(
        (const float4*)H, src, dst, AGG, N_EDGES);
    finalize_kernel<<<(int)((total4_512 + 255) / 256), 256, 0, stream>>>(
        AGG, inn, b1, 7, 1, total4_512);

    // ---- layer 2 (output 256 feats, no relu) ----
    gemm_rowscale<<<g256, 256, 0, stream>>>(AGG, W2, H, outn, N_NODES, 256, 512);
    hipMemsetAsync(out, 0, (size_t)N_NODES * 256 * sizeof(float), stream);
    scatter_add<64, 4><<<dim3((N_EDGES + 3) / 4), dim3(64, 4), 0, stream>>>(
        (const float4*)H, src, dst, out, N_EDGES);
    finalize_kernel<<<(int)((total4_256 + 255) / 256), 256, 0, stream>>>(
        out, inn, b2, 6, 0, total4_256);
}

// Round 2
// 1863.946 us; speedup vs baseline: 7.7930x; 7.7930x over previous
//
#include <hip/hip_runtime.h>

#define N_NODES 50000
#define N_EDGES 800000
// feats: 512 -> 512 -> 512 -> 256

// ---------------- int degree histograms ----------------
__global__ void hist_kernel(const int* __restrict__ src, const int* __restrict__ dst,
                            int* __restrict__ outc, int* __restrict__ inc) {
    int i = blockIdx.x * blockDim.x + threadIdx.x;
    if (i < N_EDGES) {
        atomicAdd(&outc[src[i]], 1);
        atomicAdd(&inc[dst[i]], 1);
    }
}

__global__ void norm_kernel(const int* __restrict__ outc, const int* __restrict__ inc,
                            float* __restrict__ outn, float* __restrict__ inn) {
    int i = blockIdx.x * blockDim.x + threadIdx.x;
    if (i < N_NODES) {
        outn[i] = rsqrtf(fmaxf((float)outc[i], 1.0f));
        inn[i]  = rsqrtf(fmaxf((float)inc[i], 1.0f));
    }
}

// ---------------- single-block exclusive scan over counts -> row_start ----------------
__global__ __launch_bounds__(1024) void scan_kernel(const int* __restrict__ cnt,
                                                    int* __restrict__ row_start, int n) {
    __shared__ int tmp[1024];
    const int tid = threadIdx.x;
    int carry = 0;
    for (int base = 0; base < n; base += 1024) {
        int i = base + tid;
        int v = (i < n) ? cnt[i] : 0;
        tmp[tid] = v;
        __syncthreads();
#pragma unroll
        for (int off = 1; off < 1024; off <<= 1) {
            int t = (tid >= off) ? tmp[tid - off] : 0;
            __syncthreads();
            tmp[tid] += t;
            __syncthreads();
        }
        int incl = tmp[tid];
        int chunk_total = tmp[1023];
        if (i < n) row_start[i] = carry + incl - v;
        carry += chunk_total;
        __syncthreads();
    }
    if (tid == 0) row_start[n] = carry;
}

// ---------------- CSR fill: csr_src holds src ids grouped by dst ----------------
__global__ void fill_kernel(const int* __restrict__ src, const int* __restrict__ dst,
                            const int* __restrict__ row_start, int* __restrict__ cursor,
                            int* __restrict__ csr_src) {
    int e = blockIdx.x * blockDim.x + threadIdx.x;
    if (e < N_EDGES) {
        int d = dst[e];
        int pos = atomicAdd(&cursor[d], 1);
        csr_src[row_start[d] + pos] = src[e];
    }
}

// ---------------- fp32 tiled GEMM, C = (A @ B) * rowscale[row] ----------------
__global__ __launch_bounds__(256) void gemm_rowscale(
    const float* __restrict__ A, const float* __restrict__ B,
    float* __restrict__ C, const float* __restrict__ rowscale,
    int M, int N, int K)
{
    __shared__ float sA[16][65];
    __shared__ float sB[16][64];

    const int tid = threadIdx.x;
    const int tx = tid & 15;
    const int ty = tid >> 4;
    const int rowBase = blockIdx.x * 64;
    const int colBase = blockIdx.y * 64;

    const int lar = tid >> 2;
    const int lak = (tid & 3) << 2;
    const int lbk = tid >> 4;
    const int lbc = (tid & 15) << 2;

    const int arow = rowBase + lar;
    const bool aok = (arow < M);

    float acc[4][4];
#pragma unroll
    for (int i = 0; i < 4; ++i)
#pragma unroll
        for (int j = 0; j < 4; ++j) acc[i][j] = 0.0f;

    for (int k0 = 0; k0 < K; k0 += 16) {
        float4 av = make_float4(0.f, 0.f, 0.f, 0.f);
        if (aok) av = *(const float4*)(A + (size_t)arow * K + k0 + lak);
        float4 bv = *(const float4*)(B + (size_t)(k0 + lbk) * N + colBase + lbc);

        sA[lak + 0][lar] = av.x;
        sA[lak + 1][lar] = av.y;
        sA[lak + 2][lar] = av.z;
        sA[lak + 3][lar] = av.w;
        *(float4*)&sB[lbk][lbc] = bv;
        __syncthreads();

#pragma unroll
        for (int k = 0; k < 16; ++k) {
            float a0 = sA[k][ty * 4 + 0];
            float a1 = sA[k][ty * 4 + 1];
            float a2 = sA[k][ty * 4 + 2];
            float a3 = sA[k][ty * 4 + 3];
            float4 b = *(float4*)&sB[k][tx * 4];
            acc[0][0] += a0 * b.x; acc[0][1] += a0 * b.y; acc[0][2] += a0 * b.z; acc[0][3] += a0 * b.w;
            acc[1][0] += a1 * b.x; acc[1][1] += a1 * b.y; acc[1][2] += a1 * b.z; acc[1][3] += a1 * b.w;
            acc[2][0] += a2 * b.x; acc[2][1] += a2 * b.y; acc[2][2] += a2 * b.z; acc[2][3] += a2 * b.w;
            acc[3][0] += a3 * b.x; acc[3][1] += a3 * b.y; acc[3][2] += a3 * b.z; acc[3][3] += a3 * b.w;
        }
        __syncthreads();
    }

#pragma unroll
    for (int i = 0; i < 4; ++i) {
        int r = rowBase + ty * 4 + i;
        if (r < M) {
            float s = rowscale[r];
            float4 o;
            o.x = acc[i][0] * s; o.y = acc[i][1] * s;
            o.z = acc[i][2] * s; o.w = acc[i][3] * s;
            *(float4*)(C + (size_t)r * N + colBase + tx * 4) = o;
        }
    }
}

// ---------------- gather-aggregate + norm + bias (+relu), no atomics ----------------
// One block per dst node; F4 threads, one float4 per thread.
template<int F4, int RELU>
__global__ __launch_bounds__(F4) void agg_kernel(
    const float4* __restrict__ H4, const int* __restrict__ csr_src,
    const int* __restrict__ row_start, const float* __restrict__ inn,
    const float* __restrict__ bias, float4* __restrict__ out)
{
    __shared__ int sIds[F4];
    const int d = blockIdx.x;
    const int tid = threadIdx.x;
    const int start = row_start[d];
    const int end   = row_start[d + 1];

    float4 acc = make_float4(0.f, 0.f, 0.f, 0.f);
    for (int j0 = start; j0 < end; j0 += F4) {
        int nn = min(F4, end - j0);
        if (tid < nn) sIds[tid] = csr_src[j0 + tid];
        __syncthreads();
        for (int t = 0; t < nn; ++t) {
            float4 v = H4[(size_t)sIds[t] * F4 + tid];
            acc.x += v.x; acc.y += v.y; acc.z += v.z; acc.w += v.w;
        }
        __syncthreads();
    }

    float s = inn[d];
    float4 b = ((const float4*)bias)[tid];
    float4 r;
    r.x = acc.x * s + b.x;
    r.y = acc.y * s + b.y;
    r.z = acc.z * s + b.z;
    r.w = acc.w * s + b.w;
    if (RELU) {
        r.x = fmaxf(r.x, 0.f); r.y = fmaxf(r.y, 0.f);
        r.z = fmaxf(r.z, 0.f); r.w = fmaxf(r.w, 0.f);
    }
    out[(size_t)d * F4 + tid] = r;
}

extern "C" void kernel_launch(void* const* d_in, const int* in_sizes, int n_in,
                              void* d_out, int out_size, void* d_ws, size_t ws_size,
                              hipStream_t stream) {
    const float* feat = (const float*)d_in[0];
    const int*   src  = (const int*)d_in[1];
    const int*   dst  = (const int*)d_in[2];
    const float* W0   = (const float*)d_in[3];
    const float* b0   = (const float*)d_in[4];
    const float* W1   = (const float*)d_in[5];
    const float* b1   = (const float*)d_in[6];
    const float* W2   = (const float*)d_in[7];
    const float* b2   = (const float*)d_in[8];
    float* out = (float*)d_out;

    // ---- workspace layout ----
    float* outn = (float*)d_ws;                       // [N]
    float* inn  = outn + N_NODES;                     // [N]
    int* outc      = (int*)(inn + N_NODES);           // [N]
    int* inc       = outc + N_NODES;                  // [N]
    int* cursor    = inc + N_NODES;                   // [N]
    int* row_start = cursor + N_NODES;                // [N+1]
    int* csr_src   = row_start + N_NODES + 4;         // [E]
    size_t ofs = (size_t)(csr_src + N_EDGES - (int*)d_ws);
    ofs = (ofs + 3) & ~(size_t)3;                     // 16B align
    float* H = (float*)d_ws + ofs;                    // [N,512]
    float* X = H + (size_t)N_NODES * 512;             // [N,512]

    // ---- degrees + CSR build ----
    hipMemsetAsync(outc, 0, 3 * N_NODES * sizeof(int), stream);  // outc, inc, cursor
    hist_kernel<<<(N_EDGES + 255) / 256, 256, 0, stream>>>(src, dst, outc, inc);
    norm_kernel<<<(N_NODES + 255) / 256, 256, 0, stream>>>(outc, inc, outn, inn);
    scan_kernel<<<1, 1024, 0, stream>>>(inc, row_start, N_NODES);
    fill_kernel<<<(N_EDGES + 255) / 256, 256, 0, stream>>>(src, dst, row_start, cursor, csr_src);

    dim3 g512((N_NODES + 63) / 64, 512 / 64);
    dim3 g256((N_NODES + 63) / 64, 256 / 64);

    // ---- layer 0 ----
    gemm_rowscale<<<g512, 256, 0, stream>>>(feat, W0, H, outn, N_NODES, 512, 512);
    agg_kernel<128, 1><<<N_NODES, 128, 0, stream>>>(
        (const float4*)H, csr_src, row_start, inn, b0, (float4*)X);

    // ---- layer 1 ----
    gemm_rowscale<<<g512, 256, 0, stream>>>(X, W1, H, outn, N_NODES, 512, 512);
    agg_kernel<128, 1><<<N_NODES, 128, 0, stream>>>(
        (const float4*)H, csr_src, row_start, inn, b1, (float4*)X);

    // ---- layer 2 (256 out, no relu) ----
    gemm_rowscale<<<g256, 256, 0, stream>>>(X, W2, H, outn, N_NODES, 256, 512);
    agg_kernel<64, 0><<<N_NODES, 64, 0, stream>>>(
        (const float4*)H, csr_src, row_start, inn, b2, (float4*)out);
}

// Round 3
// 1312.158 us; speedup vs baseline: 11.0702x; 1.4205x over previous
//
#include <hip/hip_runtime.h>

#define N_NODES 50000
#define N_EDGES 800000
// feats: 512 -> 512 -> 512 -> 256; K is always 512

typedef __attribute__((ext_vector_type(8))) short short8;
typedef __attribute__((ext_vector_type(4))) float f32x4;

// ---------------- bf16 split helpers ----------------
static __device__ __forceinline__ unsigned short f2bf(float f) {
    unsigned int u = __builtin_bit_cast(unsigned int, f);
    u += 0x7fff + ((u >> 16) & 1);   // RNE
    return (unsigned short)(u >> 16);
}
static __device__ __forceinline__ float bf2f(unsigned short h) {
    unsigned int u = ((unsigned int)h) << 16;
    return __builtin_bit_cast(float, u);
}
static __device__ __forceinline__ void split2(float f, unsigned short& hi, unsigned short& lo) {
    hi = f2bf(f);
    lo = f2bf(f - bf2f(hi));
}

// ---------------- int degree histograms ----------------
__global__ void hist_kernel(const int* __restrict__ src, const int* __restrict__ dst,
                            int* __restrict__ outc, int* __restrict__ inc) {
    int i = blockIdx.x * blockDim.x + threadIdx.x;
    if (i < N_EDGES) {
        atomicAdd(&outc[src[i]], 1);
        atomicAdd(&inc[dst[i]], 1);
    }
}

__global__ void norm_kernel(const int* __restrict__ outc, const int* __restrict__ inc,
                            float* __restrict__ outn, float* __restrict__ inn) {
    int i = blockIdx.x * blockDim.x + threadIdx.x;
    if (i < N_NODES) {
        outn[i] = rsqrtf(fmaxf((float)outc[i], 1.0f));
        inn[i]  = rsqrtf(fmaxf((float)inc[i], 1.0f));
    }
}

// ---------------- single-block exclusive scan ----------------
__global__ __launch_bounds__(1024) void scan_kernel(const int* __restrict__ cnt,
                                                    int* __restrict__ row_start, int n) {
    __shared__ int tmp[1024];
    const int tid = threadIdx.x;
    int carry = 0;
    for (int base = 0; base < n; base += 1024) {
        int i = base + tid;
        int v = (i < n) ? cnt[i] : 0;
        tmp[tid] = v;
        __syncthreads();
#pragma unroll
        for (int off = 1; off < 1024; off <<= 1) {
            int t = (tid >= off) ? tmp[tid - off] : 0;
            __syncthreads();
            tmp[tid] += t;
            __syncthreads();
        }
        int incl = tmp[tid];
        int chunk_total = tmp[1023];
        if (i < n) row_start[i] = carry + incl - v;
        carry += chunk_total;
        __syncthreads();
    }
    if (tid == 0) row_start[n] = carry;
}

// ---------------- CSR fill ----------------
__global__ void fill_kernel(const int* __restrict__ src, const int* __restrict__ dst,
                            const int* __restrict__ row_start, int* __restrict__ cursor,
                            int* __restrict__ csr_src) {
    int e = blockIdx.x * blockDim.x + threadIdx.x;
    if (e < N_EDGES) {
        int d = dst[e];
        int pos = atomicAdd(&cursor[d], 1);
        csr_src[row_start[d] + pos] = src[e];
    }
}

// ---------------- W [K,N] fp32 -> Wt_hi/Wt_lo [N,K] bf16 (transpose + split) ----------------
__global__ __launch_bounds__(256) void conv_W(const float* __restrict__ W,
                                              unsigned short* __restrict__ Whi,
                                              unsigned short* __restrict__ Wlo,
                                              int K, int N) {
    __shared__ float t[32][33];
    int tx = threadIdx.x & 31, ty = threadIdx.x >> 5;   // 32 x 8
    int kb = blockIdx.x * 32, nb = blockIdx.y * 32;
#pragma unroll
    for (int i = 0; i < 4; ++i)
        t[ty + 8 * i][tx] = W[(size_t)(kb + ty + 8 * i) * N + nb + tx];
    __syncthreads();
#pragma unroll
    for (int i = 0; i < 4; ++i) {
        float v = t[tx][ty + 8 * i];
        int n = nb + ty + 8 * i, k = kb + tx;
        unsigned short h, l;
        split2(v, h, l);
        Whi[(size_t)n * K + k] = h;
        Wlo[(size_t)n * K + k] = l;
    }
}

// ---------------- feat [M,512] fp32 -> (outn[row]*feat) split into Ahi/Alo ----------------
__global__ void conv_A(const float4* __restrict__ feat4, const float* __restrict__ outn,
                       ushort4* __restrict__ hi, ushort4* __restrict__ lo, long total4) {
    long i = (long)blockIdx.x * blockDim.x + threadIdx.x;
    if (i >= total4) return;
    int row = (int)(i >> 7);            // 512/4 = 128 float4 per row
    float s = outn[row];
    float4 v = feat4[i];
    ushort4 h, l;
    split2(v.x * s, h.x, l.x);
    split2(v.y * s, h.y, l.y);
    split2(v.z * s, h.z, l.z);
    split2(v.w * s, h.w, l.w);
    hi[i] = h;
    lo[i] = l;
}

// ---------------- MFMA GEMM: C[M,N] = (Ahi+Alo) @ (Bhi+Blo)^T, K=512 ----------------
// A: [M,512] bf16 hi/lo (out_norm pre-folded). B: [N,512] bf16 hi/lo (transposed W).
// 128x128 tile, BK=32, 256 threads = 4 waves, each wave 64x64 (4x4 of 16x16 MFMA).
__global__ __launch_bounds__(256) void gemm_mfma(
    const unsigned short* __restrict__ Ahi, const unsigned short* __restrict__ Alo,
    const unsigned short* __restrict__ Bhi, const unsigned short* __restrict__ Blo,
    float* __restrict__ C, int M, int N)
{
    const int K = 512;
    __shared__ unsigned short sAhi[128 * 32], sAlo[128 * 32];
    __shared__ unsigned short sBhi[128 * 32], sBlo[128 * 32];

    const int tid = threadIdx.x;
    const int rowBase = blockIdx.x * 128;
    const int colBase = blockIdx.y * 128;
    const int wave = tid >> 6;
    const int lane = tid & 63;
    const int wr = (wave >> 1) * 64;
    const int wc = (wave & 1) * 64;
    const int lrow = lane & 15;
    const int quad = lane >> 4;

    f32x4 acc[4][4] = {};

    // staging: each thread handles 2 x 16B chunks per matrix
    const int crow = tid >> 2;            // 0..63
    const int ck   = (tid & 3) * 8;       // 0,8,16,24
    const int ar0 = min(rowBase + crow, M - 1);
    const int ar1 = min(rowBase + 64 + crow, M - 1);
    const int bn0 = colBase + crow;
    const int bn1 = colBase + 64 + crow;

    for (int k0 = 0; k0 < K; k0 += 32) {
        short8 a0 = *(const short8*)&Ahi[(size_t)ar0 * K + k0 + ck];
        short8 a1 = *(const short8*)&Ahi[(size_t)ar1 * K + k0 + ck];
        short8 l0 = *(const short8*)&Alo[(size_t)ar0 * K + k0 + ck];
        short8 l1 = *(const short8*)&Alo[(size_t)ar1 * K + k0 + ck];
        short8 b0 = *(const short8*)&Bhi[(size_t)bn0 * K + k0 + ck];
        short8 b1 = *(const short8*)&Bhi[(size_t)bn1 * K + k0 + ck];
        short8 m0 = *(const short8*)&Blo[(size_t)bn0 * K + k0 + ck];
        short8 m1 = *(const short8*)&Blo[(size_t)bn1 * K + k0 + ck];
        __syncthreads();
        *(short8*)&sAhi[crow * 32 + ck] = a0;
        *(short8*)&sAhi[(64 + crow) * 32 + ck] = a1;
        *(short8*)&sAlo[crow * 32 + ck] = l0;
        *(short8*)&sAlo[(64 + crow) * 32 + ck] = l1;
        *(short8*)&sBhi[crow * 32 + ck] = b0;
        *(short8*)&sBhi[(64 + crow) * 32 + ck] = b1;
        *(short8*)&sBlo[crow * 32 + ck] = m0;
        *(short8*)&sBlo[(64 + crow) * 32 + ck] = m1;
        __syncthreads();

        short8 ah[4], al[4], bh[4], bl[4];
#pragma unroll
        for (int mt = 0; mt < 4; ++mt) {
            int off = (wr + mt * 16 + lrow) * 32 + quad * 8;
            ah[mt] = *(const short8*)&sAhi[off];
            al[mt] = *(const short8*)&sAlo[off];
        }
#pragma unroll
        for (int nt = 0; nt < 4; ++nt) {
            int off = (wc + nt * 16 + lrow) * 32 + quad * 8;
            bh[nt] = *(const short8*)&sBhi[off];
            bl[nt] = *(const short8*)&sBlo[off];
        }
#pragma unroll
        for (int mt = 0; mt < 4; ++mt)
#pragma unroll
            for (int nt = 0; nt < 4; ++nt) {
                acc[mt][nt] = __builtin_amdgcn_mfma_f32_16x16x32_bf16(ah[mt], bh[nt], acc[mt][nt], 0, 0, 0);
                acc[mt][nt] = __builtin_amdgcn_mfma_f32_16x16x32_bf16(al[mt], bh[nt], acc[mt][nt], 0, 0, 0);
                acc[mt][nt] = __builtin_amdgcn_mfma_f32_16x16x32_bf16(ah[mt], bl[nt], acc[mt][nt], 0, 0, 0);
            }
    }

    // epilogue: C/D layout col=lane&15, row=quad*4+reg
#pragma unroll
    for (int mt = 0; mt < 4; ++mt) {
        int grow0 = rowBase + wr + mt * 16 + quad * 4;
#pragma unroll
        for (int nt = 0; nt < 4; ++nt) {
            int gcol = colBase + wc + nt * 16 + lrow;
#pragma unroll
            for (int r = 0; r < 4; ++r) {
                int grow = grow0 + r;
                if (grow < M) C[(size_t)grow * N + gcol] = acc[mt][nt][r];
            }
        }
    }
}

// ---------------- gather-aggregate + norm + bias + relu -> bf16 split (next A) ----------------
template<int F4>
__global__ __launch_bounds__(F4) void agg_bf16(
    const float4* __restrict__ H4, const int* __restrict__ csr_src,
    const int* __restrict__ row_start, const float* __restrict__ inn,
    const float* __restrict__ outn, const float* __restrict__ bias,
    ushort4* __restrict__ Ahi, ushort4* __restrict__ Alo)
{
    __shared__ int sIds[F4];
    const int d = blockIdx.x;
    const int tid = threadIdx.x;
    const int start = row_start[d];
    const int end   = row_start[d + 1];

    float4 acc = make_float4(0.f, 0.f, 0.f, 0.f);
    for (int j0 = start; j0 < end; j0 += F4) {
        int nn = min(F4, end - j0);
        if (tid < nn) sIds[tid] = csr_src[j0 + tid];
        __syncthreads();
        for (int t = 0; t < nn; ++t) {
            float4 v = H4[(size_t)sIds[t] * F4 + tid];
            acc.x += v.x; acc.y += v.y; acc.z += v.z; acc.w += v.w;
        }
        __syncthreads();
    }

    float s = inn[d];
    float so = outn[d];
    float4 b = ((const float4*)bias)[tid];
    float4 r;
    r.x = fmaxf(acc.x * s + b.x, 0.f) * so;
    r.y = fmaxf(acc.y * s + b.y, 0.f) * so;
    r.z = fmaxf(acc.z * s + b.z, 0.f) * so;
    r.w = fmaxf(acc.w * s + b.w, 0.f) * so;
    ushort4 h, l;
    split2(r.x, h.x, l.x);
    split2(r.y, h.y, l.y);
    split2(r.z, h.z, l.z);
    split2(r.w, h.w, l.w);
    Ahi[(size_t)d * F4 + tid] = h;
    Alo[(size_t)d * F4 + tid] = l;
}

// ---------------- final layer aggregate: fp32 out, no relu ----------------
template<int F4>
__global__ __launch_bounds__(F4) void agg_f32(
    const float4* __restrict__ H4, const int* __restrict__ csr_src,
    const int* __restrict__ row_start, const float* __restrict__ inn,
    const float* __restrict__ bias, float4* __restrict__ out)
{
    __shared__ int sIds[F4];
    const int d = blockIdx.x;
    const int tid = threadIdx.x;
    const int start = row_start[d];
    const int end   = row_start[d + 1];

    float4 acc = make_float4(0.f, 0.f, 0.f, 0.f);
    for (int j0 = start; j0 < end; j0 += F4) {
        int nn = min(F4, end - j0);
        if (tid < nn) sIds[tid] = csr_src[j0 + tid];
        __syncthreads();
        for (int t = 0; t < nn; ++t) {
            float4 v = H4[(size_t)sIds[t] * F4 + tid];
            acc.x += v.x; acc.y += v.y; acc.z += v.z; acc.w += v.w;
        }
        __syncthreads();
    }

    float s = inn[d];
    float4 b = ((const float4*)bias)[tid];
    float4 r;
    r.x = acc.x * s + b.x;
    r.y = acc.y * s + b.y;
    r.z = acc.z * s + b.z;
    r.w = acc.w * s + b.w;
    out[(size_t)d * F4 + tid] = r;
}

extern "C" void kernel_launch(void* const* d_in, const int* in_sizes, int n_in,
                              void* d_out, int out_size, void* d_ws, size_t ws_size,
                              hipStream_t stream) {
    const float* feat = (const float*)d_in[0];
    const int*   src  = (const int*)d_in[1];
    const int*   dst  = (const int*)d_in[2];
    const float* W0   = (const float*)d_in[3];
    const float* b0   = (const float*)d_in[4];
    const float* W1   = (const float*)d_in[5];
    const float* b1   = (const float*)d_in[6];
    const float* W2   = (const float*)d_in[7];
    const float* b2   = (const float*)d_in[8];
    float* out = (float*)d_out;

    // ---- workspace bump allocator (64B aligned) ----
    char* p = (char*)d_ws;
    auto alloc = [&](size_t bytes) {
        char* r = p;
        p += (bytes + 63) & ~(size_t)63;
        return r;
    };
    float* outn = (float*)alloc(N_NODES * 4);
    float* inn  = (float*)alloc(N_NODES * 4);
    int* outc      = (int*)alloc(N_NODES * 4);
    int* inc       = (int*)alloc(N_NODES * 4);
    int* cursor    = (int*)alloc(N_NODES * 4);
    int* row_start = (int*)alloc((N_NODES + 1) * 4);
    int* csr_src   = (int*)alloc(N_EDGES * 4);
    unsigned short* W0hi = (unsigned short*)alloc(512 * 512 * 2);
    unsigned short* W0lo = (unsigned short*)alloc(512 * 512 * 2);
    unsigned short* W1hi = (unsigned short*)alloc(512 * 512 * 2);
    unsigned short* W1lo = (unsigned short*)alloc(512 * 512 * 2);
    unsigned short* W2hi = (unsigned short*)alloc(256 * 512 * 2);
    unsigned short* W2lo = (unsigned short*)alloc(256 * 512 * 2);
    unsigned short* Ahi = (unsigned short*)alloc((size_t)N_NODES * 512 * 2);
    unsigned short* Alo = (unsigned short*)alloc((size_t)N_NODES * 512 * 2);
    float* H = (float*)alloc((size_t)N_NODES * 512 * 4);

    // ---- degrees + norms + CSR ----
    hipMemsetAsync(outc, 0, 3 * N_NODES * sizeof(int), stream);  // outc, inc, cursor contiguous
    hist_kernel<<<(N_EDGES + 255) / 256, 256, 0, stream>>>(src, dst, outc, inc);
    norm_kernel<<<(N_NODES + 255) / 256, 256, 0, stream>>>(outc, inc, outn, inn);
    scan_kernel<<<1, 1024, 0, stream>>>(inc, row_start, N_NODES);
    fill_kernel<<<(N_EDGES + 255) / 256, 256, 0, stream>>>(src, dst, row_start, cursor, csr_src);

    // ---- weight transpose + split ----
    conv_W<<<dim3(16, 16), 256, 0, stream>>>(W0, W0hi, W0lo, 512, 512);
    conv_W<<<dim3(16, 16), 256, 0, stream>>>(W1, W1hi, W1lo, 512, 512);
    conv_W<<<dim3(16, 8),  256, 0, stream>>>(W2, W2hi, W2lo, 512, 256);

    // ---- feature scale + split ----
    long total4 = (long)N_NODES * 128;
    conv_A<<<(int)((total4 + 255) / 256), 256, 0, stream>>>(
        (const float4*)feat, outn, (ushort4*)Ahi, (ushort4*)Alo, total4);

    dim3 g512((N_NODES + 127) / 128, 4);
    dim3 g256((N_NODES + 127) / 128, 2);

    // ---- layer 0 ----
    gemm_mfma<<<g512, 256, 0, stream>>>(Ahi, Alo, W0hi, W0lo, H, N_NODES, 512);
    agg_bf16<128><<<N_NODES, 128, 0, stream>>>(
        (const float4*)H, csr_src, row_start, inn, outn, b0, (ushort4*)Ahi, (ushort4*)Alo);

    // ---- layer 1 ----
    gemm_mfma<<<g512, 256, 0, stream>>>(Ahi, Alo, W1hi, W1lo, H, N_NODES, 512);
    agg_bf16<128><<<N_NODES, 128, 0, stream>>>(
        (const float4*)H, csr_src, row_start, inn, outn, b1, (ushort4*)Ahi, (ushort4*)Alo);

    // ---- layer 2 (256 out, no relu, fp32) ----
    gemm_mfma<<<g256, 256, 0, stream>>>(Ahi, Alo, W2hi, W2lo, H, N_NODES, 256);
    agg_f32<64><<<N_NODES, 64, 0, stream>>>(
        (const float4*)H, csr_src, row_start, inn, b2, (float4*)out);
}

// Round 4
// 963.741 us; speedup vs baseline: 15.0723x; 1.3615x over previous
//
#include <hip/hip_runtime.h>

#define N_NODES 50000
#define N_EDGES 800000
// feats: 512 -> 512 -> 512 -> 256; K is always 512

typedef __attribute__((ext_vector_type(8))) short short8;
typedef __attribute__((ext_vector_type(4))) float f32x4;

// ---------------- bf16 helpers ----------------
static __device__ __forceinline__ unsigned short f2bf(float f) {
    unsigned int u = __builtin_bit_cast(unsigned int, f);
    u += 0x7fff + ((u >> 16) & 1);   // RNE
    return (unsigned short)(u >> 16);
}
static __device__ __forceinline__ float bf2f(unsigned short h) {
    unsigned int u = ((unsigned int)h) << 16;
    return __builtin_bit_cast(float, u);
}
static __device__ __forceinline__ void split2(float f, unsigned short& hi, unsigned short& lo) {
    hi = f2bf(f);
    lo = f2bf(f - bf2f(hi));
}

// ---------------- int degree histograms ----------------
__global__ void hist_kernel(const int* __restrict__ src, const int* __restrict__ dst,
                            int* __restrict__ outc, int* __restrict__ inc) {
    int i = blockIdx.x * blockDim.x + threadIdx.x;
    if (i < N_EDGES) {
        atomicAdd(&outc[src[i]], 1);
        atomicAdd(&inc[dst[i]], 1);
    }
}

__global__ void norm_kernel(const int* __restrict__ outc, const int* __restrict__ inc,
                            float* __restrict__ outn, float* __restrict__ inn) {
    int i = blockIdx.x * blockDim.x + threadIdx.x;
    if (i < N_NODES) {
        outn[i] = rsqrtf(fmaxf((float)outc[i], 1.0f));
        inn[i]  = rsqrtf(fmaxf((float)inc[i], 1.0f));
    }
}

// ---------------- single-block exclusive scan ----------------
__global__ __launch_bounds__(1024) void scan_kernel(const int* __restrict__ cnt,
                                                    int* __restrict__ row_start, int n) {
    __shared__ int tmp[1024];
    const int tid = threadIdx.x;
    int carry = 0;
    for (int base = 0; base < n; base += 1024) {
        int i = base + tid;
        int v = (i < n) ? cnt[i] : 0;
        tmp[tid] = v;
        __syncthreads();
#pragma unroll
        for (int off = 1; off < 1024; off <<= 1) {
            int t = (tid >= off) ? tmp[tid - off] : 0;
            __syncthreads();
            tmp[tid] += t;
            __syncthreads();
        }
        int incl = tmp[tid];
        int chunk_total = tmp[1023];
        if (i < n) row_start[i] = carry + incl - v;
        carry += chunk_total;
        __syncthreads();
    }
    if (tid == 0) row_start[n] = carry;
}

// ---------------- CSR fill ----------------
__global__ void fill_kernel(const int* __restrict__ src, const int* __restrict__ dst,
                            const int* __restrict__ row_start, int* __restrict__ cursor,
                            int* __restrict__ csr_src) {
    int e = blockIdx.x * blockDim.x + threadIdx.x;
    if (e < N_EDGES) {
        int d = dst[e];
        int pos = atomicAdd(&cursor[d], 1);
        csr_src[row_start[d] + pos] = src[e];
    }
}

// ---------------- W [K,N] fp32 -> Wt_hi/Wt_lo [N,K] bf16 (transpose + split) ----------------
__global__ __launch_bounds__(256) void conv_W(const float* __restrict__ W,
                                              unsigned short* __restrict__ Whi,
                                              unsigned short* __restrict__ Wlo,
                                              int K, int N) {
    __shared__ float t[32][33];
    int tx = threadIdx.x & 31, ty = threadIdx.x >> 5;   // 32 x 8
    int kb = blockIdx.x * 32, nb = blockIdx.y * 32;
#pragma unroll
    for (int i = 0; i < 4; ++i)
        t[ty + 8 * i][tx] = W[(size_t)(kb + ty + 8 * i) * N + nb + tx];
    __syncthreads();
#pragma unroll
    for (int i = 0; i < 4; ++i) {
        float v = t[tx][ty + 8 * i];
        int n = nb + ty + 8 * i, k = kb + tx;
        unsigned short h, l;
        split2(v, h, l);
        Whi[(size_t)n * K + k] = h;
        Wlo[(size_t)n * K + k] = l;
    }
}

// ---------------- feat [M,512] fp32 -> (outn[row]*feat) split into Ahi/Alo ----------------
__global__ void conv_A(const float4* __restrict__ feat4, const float* __restrict__ outn,
                       ushort4* __restrict__ hi, ushort4* __restrict__ lo, long total4) {
    long i = (long)blockIdx.x * blockDim.x + threadIdx.x;
    if (i >= total4) return;
    int row = (int)(i >> 7);            // 512/4 = 128 float4 per row
    float s = outn[row];
    float4 v = feat4[i];
    ushort4 h, l;
    split2(v.x * s, h.x, l.x);
    split2(v.y * s, h.y, l.y);
    split2(v.z * s, h.z, l.z);
    split2(v.w * s, h.w, l.w);
    hi[i] = h;
    lo[i] = l;
}

// ---------------- MFMA GEMM: C[M,N] = (Ahi+Alo) @ (Bhi+Blo)^T, K=512, C in bf16 ----------------
// A: [M,512] bf16 hi/lo (out_norm pre-folded). B: [N,512] bf16 hi/lo (transposed W).
// 128x128 tile, BK=32, 256 threads = 4 waves, each wave 64x64 (4x4 of 16x16 MFMA).
__global__ __launch_bounds__(256) void gemm_mfma(
    const unsigned short* __restrict__ Ahi, const unsigned short* __restrict__ Alo,
    const unsigned short* __restrict__ Bhi, const unsigned short* __restrict__ Blo,
    unsigned short* __restrict__ C, int M, int N)
{
    const int K = 512;
    __shared__ unsigned short sAhi[128 * 32], sAlo[128 * 32];
    __shared__ unsigned short sBhi[128 * 32], sBlo[128 * 32];

    const int tid = threadIdx.x;
    const int rowBase = blockIdx.x * 128;
    const int colBase = blockIdx.y * 128;
    const int wave = tid >> 6;
    const int lane = tid & 63;
    const int wr = (wave >> 1) * 64;
    const int wc = (wave & 1) * 64;
    const int lrow = lane & 15;
    const int quad = lane >> 4;

    f32x4 acc[4][4] = {};

    const int crow = tid >> 2;            // 0..63
    const int ck   = (tid & 3) * 8;       // 0,8,16,24
    const int ar0 = min(rowBase + crow, M - 1);
    const int ar1 = min(rowBase + 64 + crow, M - 1);
    const int bn0 = colBase + crow;
    const int bn1 = colBase + 64 + crow;

    for (int k0 = 0; k0 < K; k0 += 32) {
        short8 a0 = *(const short8*)&Ahi[(size_t)ar0 * K + k0 + ck];
        short8 a1 = *(const short8*)&Ahi[(size_t)ar1 * K + k0 + ck];
        short8 l0 = *(const short8*)&Alo[(size_t)ar0 * K + k0 + ck];
        short8 l1 = *(const short8*)&Alo[(size_t)ar1 * K + k0 + ck];
        short8 b0 = *(const short8*)&Bhi[(size_t)bn0 * K + k0 + ck];
        short8 b1 = *(const short8*)&Bhi[(size_t)bn1 * K + k0 + ck];
        short8 m0 = *(const short8*)&Blo[(size_t)bn0 * K + k0 + ck];
        short8 m1 = *(const short8*)&Blo[(size_t)bn1 * K + k0 + ck];
        __syncthreads();
        *(short8*)&sAhi[crow * 32 + ck] = a0;
        *(short8*)&sAhi[(64 + crow) * 32 + ck] = a1;
        *(short8*)&sAlo[crow * 32 + ck] = l0;
        *(short8*)&sAlo[(64 + crow) * 32 + ck] = l1;
        *(short8*)&sBhi[crow * 32 + ck] = b0;
        *(short8*)&sBhi[(64 + crow) * 32 + ck] = b1;
        *(short8*)&sBlo[crow * 32 + ck] = m0;
        *(short8*)&sBlo[(64 + crow) * 32 + ck] = m1;
        __syncthreads();

        short8 ah[4], al[4], bh[4], bl[4];
#pragma unroll
        for (int mt = 0; mt < 4; ++mt) {
            int off = (wr + mt * 16 + lrow) * 32 + quad * 8;
            ah[mt] = *(const short8*)&sAhi[off];
            al[mt] = *(const short8*)&sAlo[off];
        }
#pragma unroll
        for (int nt = 0; nt < 4; ++nt) {
            int off = (wc + nt * 16 + lrow) * 32 + quad * 8;
            bh[nt] = *(const short8*)&sBhi[off];
            bl[nt] = *(const short8*)&sBlo[off];
        }
#pragma unroll
        for (int mt = 0; mt < 4; ++mt)
#pragma unroll
            for (int nt = 0; nt < 4; ++nt) {
                acc[mt][nt] = __builtin_amdgcn_mfma_f32_16x16x32_bf16(ah[mt], bh[nt], acc[mt][nt], 0, 0, 0);
                acc[mt][nt] = __builtin_amdgcn_mfma_f32_16x16x32_bf16(al[mt], bh[nt], acc[mt][nt], 0, 0, 0);
                acc[mt][nt] = __builtin_amdgcn_mfma_f32_16x16x32_bf16(ah[mt], bl[nt], acc[mt][nt], 0, 0, 0);
            }
    }

    // epilogue: C/D layout col=lane&15, row=quad*4+reg; store bf16
#pragma unroll
    for (int mt = 0; mt < 4; ++mt) {
        int grow0 = rowBase + wr + mt * 16 + quad * 4;
#pragma unroll
        for (int nt = 0; nt < 4; ++nt) {
            int gcol = colBase + wc + nt * 16 + lrow;
#pragma unroll
            for (int r = 0; r < 4; ++r) {
                int grow = grow0 + r;
                if (grow < M) C[(size_t)grow * N + gcol] = f2bf(acc[mt][nt][r]);
            }
        }
    }
}

// ---------------- gather-aggregate (bf16 H) + norm + bias + relu -> bf16 split (next A) ----------------
// F4 threads, one ushort4 (4 feats) per thread. F = F4*4.
template<int F4>
__global__ __launch_bounds__(F4) void agg_bf16(
    const ushort4* __restrict__ H4, const int* __restrict__ csr_src,
    const int* __restrict__ row_start, const float* __restrict__ inn,
    const float* __restrict__ outn, const float* __restrict__ bias,
    ushort4* __restrict__ Ahi, ushort4* __restrict__ Alo)
{
    __shared__ int sIds[F4];
    const int d = blockIdx.x;
    const int tid = threadIdx.x;
    const int start = row_start[d];
    const int end   = row_start[d + 1];

    float4 acc = make_float4(0.f, 0.f, 0.f, 0.f);
    for (int j0 = start; j0 < end; j0 += F4) {
        int nn = min(F4, end - j0);
        if (tid < nn) sIds[tid] = csr_src[j0 + tid];
        __syncthreads();
        for (int t = 0; t < nn; ++t) {
            ushort4 u = H4[(size_t)sIds[t] * F4 + tid];
            acc.x += bf2f(u.x); acc.y += bf2f(u.y);
            acc.z += bf2f(u.z); acc.w += bf2f(u.w);
        }
        __syncthreads();
    }

    float s = inn[d];
    float so = outn[d];
    float4 b = ((const float4*)bias)[tid];
    float4 r;
    r.x = fmaxf(acc.x * s + b.x, 0.f) * so;
    r.y = fmaxf(acc.y * s + b.y, 0.f) * so;
    r.z = fmaxf(acc.z * s + b.z, 0.f) * so;
    r.w = fmaxf(acc.w * s + b.w, 0.f) * so;
    ushort4 h, l;
    split2(r.x, h.x, l.x);
    split2(r.y, h.y, l.y);
    split2(r.z, h.z, l.z);
    split2(r.w, h.w, l.w);
    Ahi[(size_t)d * F4 + tid] = h;
    Alo[(size_t)d * F4 + tid] = l;
}

// ---------------- final layer aggregate: bf16 H -> fp32 out, no relu ----------------
template<int F4>
__global__ __launch_bounds__(F4) void agg_f32(
    const ushort4* __restrict__ H4, const int* __restrict__ csr_src,
    const int* __restrict__ row_start, const float* __restrict__ inn,
    const float* __restrict__ bias, float4* __restrict__ out)
{
    __shared__ int sIds[F4];
    const int d = blockIdx.x;
    const int tid = threadIdx.x;
    const int start = row_start[d];
    const int end   = row_start[d + 1];

    float4 acc = make_float4(0.f, 0.f, 0.f, 0.f);
    for (int j0 = start; j0 < end; j0 += F4) {
        int nn = min(F4, end - j0);
        if (tid < nn) sIds[tid] = csr_src[j0 + tid];
        __syncthreads();
        for (int t = 0; t < nn; ++t) {
            ushort4 u = H4[(size_t)sIds[t] * F4 + tid];
            acc.x += bf2f(u.x); acc.y += bf2f(u.y);
            acc.z += bf2f(u.z); acc.w += bf2f(u.w);
        }
        __syncthreads();
    }

    float s = inn[d];
    float4 b = ((const float4*)bias)[tid];
    float4 r;
    r.x = acc.x * s + b.x;
    r.y = acc.y * s + b.y;
    r.z = acc.z * s + b.z;
    r.w = acc.w * s + b.w;
    out[(size_t)d * F4 + tid] = r;
}

extern "C" void kernel_launch(void* const* d_in, const int* in_sizes, int n_in,
                              void* d_out, int out_size, void* d_ws, size_t ws_size,
                              hipStream_t stream) {
    const float* feat = (const float*)d_in[0];
    const int*   src  = (const int*)d_in[1];
    const int*   dst  = (const int*)d_in[2];
    const float* W0   = (const float*)d_in[3];
    const float* b0   = (const float*)d_in[4];
    const float* W1   = (const float*)d_in[5];
    const float* b1   = (const float*)d_in[6];
    const float* W2   = (const float*)d_in[7];
    const float* b2   = (const float*)d_in[8];
    float* out = (float*)d_out;

    // ---- workspace bump allocator (64B aligned) ----
    char* p = (char*)d_ws;
    auto alloc = [&](size_t bytes) {
        char* r = p;
        p += (bytes + 63) & ~(size_t)63;
        return r;
    };
    float* outn = (float*)alloc(N_NODES * 4);
    float* inn  = (float*)alloc(N_NODES * 4);
    int* outc      = (int*)alloc(N_NODES * 4);
    int* inc       = (int*)alloc(N_NODES * 4);
    int* cursor    = (int*)alloc(N_NODES * 4);
    int* row_start = (int*)alloc((N_NODES + 1) * 4);
    int* csr_src   = (int*)alloc(N_EDGES * 4);
    unsigned short* W0hi = (unsigned short*)alloc(512 * 512 * 2);
    unsigned short* W0lo = (unsigned short*)alloc(512 * 512 * 2);
    unsigned short* W1hi = (unsigned short*)alloc(512 * 512 * 2);
    unsigned short* W1lo = (unsigned short*)alloc(512 * 512 * 2);
    unsigned short* W2hi = (unsigned short*)alloc(256 * 512 * 2);
    unsigned short* W2lo = (unsigned short*)alloc(256 * 512 * 2);
    unsigned short* Ahi = (unsigned short*)alloc((size_t)N_NODES * 512 * 2);
    unsigned short* Alo = (unsigned short*)alloc((size_t)N_NODES * 512 * 2);
    unsigned short* H   = (unsigned short*)alloc((size_t)N_NODES * 512 * 2);

    // ---- degrees + norms + CSR ----
    hipMemsetAsync(outc, 0, 3 * N_NODES * sizeof(int), stream);  // outc, inc, cursor contiguous
    hist_kernel<<<(N_EDGES + 255) / 256, 256, 0, stream>>>(src, dst, outc, inc);
    norm_kernel<<<(N_NODES + 255) / 256, 256, 0, stream>>>(outc, inc, outn, inn);
    scan_kernel<<<1, 1024, 0, stream>>>(inc, row_start, N_NODES);
    fill_kernel<<<(N_EDGES + 255) / 256, 256, 0, stream>>>(src, dst, row_start, cursor, csr_src);

    // ---- weight transpose + split ----
    conv_W<<<dim3(16, 16), 256, 0, stream>>>(W0, W0hi, W0lo, 512, 512);
    conv_W<<<dim3(16, 16), 256, 0, stream>>>(W1, W1hi, W1lo, 512, 512);
    conv_W<<<dim3(16, 8),  256, 0, stream>>>(W2, W2hi, W2lo, 512, 256);

    // ---- feature scale + split ----
    long total4 = (long)N_NODES * 128;
    conv_A<<<(int)((total4 + 255) / 256), 256, 0, stream>>>(
        (const float4*)feat, outn, (ushort4*)Ahi, (ushort4*)Alo, total4);

    dim3 g512((N_NODES + 127) / 128, 4);
    dim3 g256((N_NODES + 127) / 128, 2);

    // ---- layer 0 ----
    gemm_mfma<<<g512, 256, 0, stream>>>(Ahi, Alo, W0hi, W0lo, H, N_NODES, 512);
    agg_bf16<128><<<N_NODES, 128, 0, stream>>>(
        (const ushort4*)H, csr_src, row_start, inn, outn, b0, (ushort4*)Ahi, (ushort4*)Alo);

    // ---- layer 1 ----
    gemm_mfma<<<g512, 256, 0, stream>>>(Ahi, Alo, W1hi, W1lo, H, N_NODES, 512);
    agg_bf16<128><<<N_NODES, 128, 0, stream>>>(
        (const ushort4*)H, csr_src, row_start, inn, outn, b1, (ushort4*)Ahi, (ushort4*)Alo);

    // ---- layer 2 (256 out, no relu, fp32) ----
    gemm_mfma<<<g256, 256, 0, stream>>>(Ahi, Alo, W2hi, W2lo, H, N_NODES, 256);
    agg_f32<64><<<N_NODES, 64, 0, stream>>>(
        (const ushort4*)H, csr_src, row_start, inn, b2, (float4*)out);
}

// Round 5
// 914.706 us; speedup vs baseline: 15.8803x; 1.0536x over previous
//
#include <hip/hip_runtime.h>

#define N_NODES 50000
#define N_EDGES 800000
// feats: 512 -> 512 -> 512 -> 256; K is always 512

typedef __attribute__((ext_vector_type(8))) short short8;
typedef __attribute__((ext_vector_type(8))) unsigned short ushort8;
typedef __attribute__((ext_vector_type(4))) float f32x4;

// ---------------- bf16 helpers ----------------
static __device__ __forceinline__ unsigned short f2bf(float f) {
    unsigned int u = __builtin_bit_cast(unsigned int, f);
    u += 0x7fff + ((u >> 16) & 1);   // RNE
    return (unsigned short)(u >> 16);
}
static __device__ __forceinline__ float bf2f(unsigned short h) {
    unsigned int u = ((unsigned int)h) << 16;
    return __builtin_bit_cast(float, u);
}
static __device__ __forceinline__ void split2(float f, unsigned short& hi, unsigned short& lo) {
    hi = f2bf(f);
    lo = f2bf(f - bf2f(hi));
}

// async global->LDS, 16B per lane (wave-uniform LDS base + lane*16 layout)
static __device__ __forceinline__ void async16(unsigned short* lds, const unsigned short* g) {
    __builtin_amdgcn_global_load_lds(
        (const __attribute__((address_space(1))) void*)g,
        (__attribute__((address_space(3))) void*)lds, 16, 0, 0);
}

// ---------------- int degree histograms ----------------
__global__ void hist_kernel(const int* __restrict__ src, const int* __restrict__ dst,
                            int* __restrict__ outc, int* __restrict__ inc) {
    int i = blockIdx.x * blockDim.x + threadIdx.x;
    if (i < N_EDGES) {
        atomicAdd(&outc[src[i]], 1);
        atomicAdd(&inc[dst[i]], 1);
    }
}

__global__ void norm_kernel(const int* __restrict__ outc, const int* __restrict__ inc,
                            float* __restrict__ outn, float* __restrict__ inn) {
    int i = blockIdx.x * blockDim.x + threadIdx.x;
    if (i < N_NODES) {
        outn[i] = rsqrtf(fmaxf((float)outc[i], 1.0f));
        inn[i]  = rsqrtf(fmaxf((float)inc[i], 1.0f));
    }
}

// ---------------- hierarchical exclusive scan (3 kernels) ----------------
__global__ __launch_bounds__(256) void scan1(const int* __restrict__ cnt,
                                             int* __restrict__ row_start,
                                             int* __restrict__ bsum, int n) {
    __shared__ int t[256];
    int tid = threadIdx.x;
    int i = blockIdx.x * 256 + tid;
    int v = (i < n) ? cnt[i] : 0;
    t[tid] = v;
    __syncthreads();
#pragma unroll
    for (int off = 1; off < 256; off <<= 1) {
        int x = (tid >= off) ? t[tid - off] : 0;
        __syncthreads();
        t[tid] += x;
        __syncthreads();
    }
    if (i < n) row_start[i] = t[tid] - v;
    if (tid == 255) bsum[blockIdx.x] = t[255];
}

__global__ __launch_bounds__(256) void scan2(int* __restrict__ bsum,
                                             int* __restrict__ boff,
                                             int* __restrict__ row_start, int nb) {
    __shared__ int t[256];
    int tid = threadIdx.x;
    int v = (tid < nb) ? bsum[tid] : 0;
    t[tid] = v;
    __syncthreads();
#pragma unroll
    for (int off = 1; off < 256; off <<= 1) {
        int x = (tid >= off) ? t[tid - off] : 0;
        __syncthreads();
        t[tid] += x;
        __syncthreads();
    }
    if (tid < nb) boff[tid] = t[tid] - v;
    if (tid == 0) row_start[N_NODES] = N_EDGES;
}

__global__ __launch_bounds__(256) void scan3(int* __restrict__ row_start,
                                             const int* __restrict__ boff, int n) {
    int i = blockIdx.x * 256 + threadIdx.x;
    if (i < n) row_start[i] += boff[blockIdx.x];
}

// ---------------- CSR fill ----------------
__global__ void fill_kernel(const int* __restrict__ src, const int* __restrict__ dst,
                            const int* __restrict__ row_start, int* __restrict__ cursor,
                            int* __restrict__ csr_src) {
    int e = blockIdx.x * blockDim.x + threadIdx.x;
    if (e < N_EDGES) {
        int d = dst[e];
        int pos = atomicAdd(&cursor[d], 1);
        csr_src[row_start[d] + pos] = src[e];
    }
}

// ---------------- W [K,N] fp32 -> Wt_hi/Wt_lo [N,K] bf16 (transpose + split) ----------------
__global__ __launch_bounds__(256) void conv_W(const float* __restrict__ W,
                                              unsigned short* __restrict__ Whi,
                                              unsigned short* __restrict__ Wlo,
                                              int K, int N) {
    __shared__ float t[32][33];
    int tx = threadIdx.x & 31, ty = threadIdx.x >> 5;   // 32 x 8
    int kb = blockIdx.x * 32, nb = blockIdx.y * 32;
#pragma unroll
    for (int i = 0; i < 4; ++i)
        t[ty + 8 * i][tx] = W[(size_t)(kb + ty + 8 * i) * N + nb + tx];
    __syncthreads();
#pragma unroll
    for (int i = 0; i < 4; ++i) {
        float v = t[tx][ty + 8 * i];
        int n = nb + ty + 8 * i, k = kb + tx;
        unsigned short h, l;
        split2(v, h, l);
        Whi[(size_t)n * K + k] = h;
        Wlo[(size_t)n * K + k] = l;
    }
}

// ---------------- feat [M,512] fp32 -> (outn[row]*feat) split into Ahi/Alo ----------------
__global__ void conv_A(const float4* __restrict__ feat4, const float* __restrict__ outn,
                       ushort4* __restrict__ hi, ushort4* __restrict__ lo, long total4) {
    long i = (long)blockIdx.x * blockDim.x + threadIdx.x;
    if (i >= total4) return;
    int row = (int)(i >> 7);            // 512/4 = 128 float4 per row
    float s = outn[row];
    float4 v = feat4[i];
    ushort4 h, l;
    split2(v.x * s, h.x, l.x);
    split2(v.y * s, h.y, l.y);
    split2(v.z * s, h.z, l.z);
    split2(v.w * s, h.w, l.w);
    hi[i] = h;
    lo[i] = l;
}

// ---------------- MFMA GEMM: C[M,N] = (Ahi+Alo) @ (Bhi+Blo)^T, K=512, C in bf16 ----------------
// 128x128 tile, BK=32, 256 threads = 4 waves; global_load_lds (16B) staging.
__global__ __launch_bounds__(256) void gemm_mfma(
    const unsigned short* __restrict__ Ahi, const unsigned short* __restrict__ Alo,
    const unsigned short* __restrict__ Bhi, const unsigned short* __restrict__ Blo,
    unsigned short* __restrict__ C, int M, int N)
{
    const int K = 512;
    __shared__ unsigned short sAhi[128 * 32], sAlo[128 * 32];
    __shared__ unsigned short sBhi[128 * 32], sBlo[128 * 32];

    const int tid = threadIdx.x;
    const int rowBase = blockIdx.x * 128;
    const int colBase = blockIdx.y * 128;
    const int wave = tid >> 6;
    const int lane = tid & 63;
    const int wr = (wave >> 1) * 64;
    const int wc = (wave & 1) * 64;
    const int lrow = lane & 15;
    const int quad = lane >> 4;

    f32x4 acc[4][4] = {};

    // staging: thread tid -> row tid>>2 (and +64), k-chunk (tid&3)*8; LDS dest = tid*16 B
    const int crow = tid >> 2;
    const int ck   = (tid & 3) * 8;
    const int ar0 = min(rowBase + crow, M - 1);
    const int ar1 = min(rowBase + 64 + crow, M - 1);
    const int bn0 = colBase + crow;
    const int bn1 = colBase + 64 + crow;
    const int ldsOf0 = tid * 8;          // ushort units
    const int ldsOf1 = 64 * 32 + tid * 8;

    for (int k0 = 0; k0 < K; k0 += 32) {
        __syncthreads();   // previous tile's compute done before overwrite
        async16(sAhi + ldsOf0, Ahi + (size_t)ar0 * K + k0 + ck);
        async16(sAhi + ldsOf1, Ahi + (size_t)ar1 * K + k0 + ck);
        async16(sAlo + ldsOf0, Alo + (size_t)ar0 * K + k0 + ck);
        async16(sAlo + ldsOf1, Alo + (size_t)ar1 * K + k0 + ck);
        async16(sBhi + ldsOf0, Bhi + (size_t)bn0 * K + k0 + ck);
        async16(sBhi + ldsOf1, Bhi + (size_t)bn1 * K + k0 + ck);
        async16(sBlo + ldsOf0, Blo + (size_t)bn0 * K + k0 + ck);
        async16(sBlo + ldsOf1, Blo + (size_t)bn1 * K + k0 + ck);
        __syncthreads();   // drains vmcnt (global_load_lds) + barrier

        short8 ah[4], al[4], bh[4], bl[4];
#pragma unroll
        for (int mt = 0; mt < 4; ++mt) {
            int off = (wr + mt * 16 + lrow) * 32 + quad * 8;
            ah[mt] = *(const short8*)&sAhi[off];
            al[mt] = *(const short8*)&sAlo[off];
        }
#pragma unroll
        for (int nt = 0; nt < 4; ++nt) {
            int off = (wc + nt * 16 + lrow) * 32 + quad * 8;
            bh[nt] = *(const short8*)&sBhi[off];
            bl[nt] = *(const short8*)&sBlo[off];
        }
#pragma unroll
        for (int mt = 0; mt < 4; ++mt)
#pragma unroll
            for (int nt = 0; nt < 4; ++nt) {
                acc[mt][nt] = __builtin_amdgcn_mfma_f32_16x16x32_bf16(ah[mt], bh[nt], acc[mt][nt], 0, 0, 0);
                acc[mt][nt] = __builtin_amdgcn_mfma_f32_16x16x32_bf16(al[mt], bh[nt], acc[mt][nt], 0, 0, 0);
                acc[mt][nt] = __builtin_amdgcn_mfma_f32_16x16x32_bf16(ah[mt], bl[nt], acc[mt][nt], 0, 0, 0);
            }
    }

    // epilogue: C/D layout col=lane&15, row=quad*4+reg; store bf16
#pragma unroll
    for (int mt = 0; mt < 4; ++mt) {
        int grow0 = rowBase + wr + mt * 16 + quad * 4;
#pragma unroll
        for (int nt = 0; nt < 4; ++nt) {
            int gcol = colBase + wc + nt * 16 + lrow;
#pragma unroll
            for (int r = 0; r < 4; ++r) {
                int grow = grow0 + r;
                if (grow < M) C[(size_t)grow * N + gcol] = f2bf(acc[mt][nt][r]);
            }
        }
    }
}

// ---------------- gather-aggregate (bf16 H, 512 feats) -> bf16 split (next A) ----------------
// 64 threads, 8 feats (16B) per lane; ids via uniform s_loads; unroll x4 for MLP.
__global__ __launch_bounds__(64) void agg_bf16_512(
    const unsigned short* __restrict__ H, const int* __restrict__ csr_src,
    const int* __restrict__ row_start, const float* __restrict__ inn,
    const float* __restrict__ outn, const float* __restrict__ bias,
    ushort8* __restrict__ Ahi, ushort8* __restrict__ Alo)
{
    const int d = blockIdx.x;
    const int tid = threadIdx.x;
    const int start = row_start[d];
    const int end   = row_start[d + 1];
    const unsigned short* Hb = H + tid * 8;

    float acc[8] = {};
    int j = start;
    for (; j + 4 <= end; j += 4) {
        int i0 = csr_src[j + 0], i1 = csr_src[j + 1];
        int i2 = csr_src[j + 2], i3 = csr_src[j + 3];
        ushort8 u0 = *(const ushort8*)(Hb + (size_t)i0 * 512);
        ushort8 u1 = *(const ushort8*)(Hb + (size_t)i1 * 512);
        ushort8 u2 = *(const ushort8*)(Hb + (size_t)i2 * 512);
        ushort8 u3 = *(const ushort8*)(Hb + (size_t)i3 * 512);
#pragma unroll
        for (int q = 0; q < 8; ++q) {
            acc[q] += bf2f(u0[q]);
            acc[q] += bf2f(u1[q]);
            acc[q] += bf2f(u2[q]);
            acc[q] += bf2f(u3[q]);
        }
    }
    for (; j < end; ++j) {
        int i0 = csr_src[j];
        ushort8 u0 = *(const ushort8*)(Hb + (size_t)i0 * 512);
#pragma unroll
        for (int q = 0; q < 8; ++q) acc[q] += bf2f(u0[q]);
    }

    float s = inn[d];
    float so = outn[d];
    float b[8];
    *(float4*)&b[0] = ((const float4*)bias)[tid * 2 + 0];
    *(float4*)&b[4] = ((const float4*)bias)[tid * 2 + 1];
    ushort8 h, l;
#pragma unroll
    for (int q = 0; q < 8; ++q) {
        float r = fmaxf(acc[q] * s + b[q], 0.f) * so;
        unsigned short rh, rl;
        split2(r, rh, rl);
        h[q] = rh;
        l[q] = rl;
    }
    Ahi[(size_t)d * 64 + tid] = h;
    Alo[(size_t)d * 64 + tid] = l;
}

// ---------------- final aggregate (bf16 H, 256 feats) -> fp32 out, no relu ----------------
__global__ __launch_bounds__(64) void agg_f32_256(
    const unsigned short* __restrict__ H, const int* __restrict__ csr_src,
    const int* __restrict__ row_start, const float* __restrict__ inn,
    const float* __restrict__ bias, float4* __restrict__ out)
{
    const int d = blockIdx.x;
    const int tid = threadIdx.x;
    const int start = row_start[d];
    const int end   = row_start[d + 1];
    const unsigned short* Hb = H + tid * 4;

    float acc[4] = {};
    int j = start;
    for (; j + 4 <= end; j += 4) {
        int i0 = csr_src[j + 0], i1 = csr_src[j + 1];
        int i2 = csr_src[j + 2], i3 = csr_src[j + 3];
        ushort4 u0 = *(const ushort4*)(Hb + (size_t)i0 * 256);
        ushort4 u1 = *(const ushort4*)(Hb + (size_t)i1 * 256);
        ushort4 u2 = *(const ushort4*)(Hb + (size_t)i2 * 256);
        ushort4 u3 = *(const ushort4*)(Hb + (size_t)i3 * 256);
        acc[0] += bf2f(u0.x) + bf2f(u1.x) + bf2f(u2.x) + bf2f(u3.x);
        acc[1] += bf2f(u0.y) + bf2f(u1.y) + bf2f(u2.y) + bf2f(u3.y);
        acc[2] += bf2f(u0.z) + bf2f(u1.z) + bf2f(u2.z) + bf2f(u3.z);
        acc[3] += bf2f(u0.w) + bf2f(u1.w) + bf2f(u2.w) + bf2f(u3.w);
    }
    for (; j < end; ++j) {
        ushort4 u0 = *(const ushort4*)(Hb + (size_t)csr_src[j] * 256);
        acc[0] += bf2f(u0.x); acc[1] += bf2f(u0.y);
        acc[2] += bf2f(u0.z); acc[3] += bf2f(u0.w);
    }

    float s = inn[d];
    float4 b = ((const float4*)bias)[tid];
    float4 r;
    r.x = acc[0] * s + b.x;
    r.y = acc[1] * s + b.y;
    r.z = acc[2] * s + b.z;
    r.w = acc[3] * s + b.w;
    out[(size_t)d * 64 + tid] = r;
}

extern "C" void kernel_launch(void* const* d_in, const int* in_sizes, int n_in,
                              void* d_out, int out_size, void* d_ws, size_t ws_size,
                              hipStream_t stream) {
    const float* feat = (const float*)d_in[0];
    const int*   src  = (const int*)d_in[1];
    const int*   dst  = (const int*)d_in[2];
    const float* W0   = (const float*)d_in[3];
    const float* b0   = (const float*)d_in[4];
    const float* W1   = (const float*)d_in[5];
    const float* b1   = (const float*)d_in[6];
    const float* W2   = (const float*)d_in[7];
    const float* b2   = (const float*)d_in[8];
    float* out = (float*)d_out;

    // ---- workspace bump allocator (64B aligned) ----
    char* p = (char*)d_ws;
    auto alloc = [&](size_t bytes) {
        char* r = p;
        p += (bytes + 63) & ~(size_t)63;
        return r;
    };
    float* outn = (float*)alloc(N_NODES * 4);
    float* inn  = (float*)alloc(N_NODES * 4);
    int* outc      = (int*)alloc(N_NODES * 4);
    int* inc       = (int*)alloc(N_NODES * 4);
    int* cursor    = (int*)alloc(N_NODES * 4);
    int* row_start = (int*)alloc((N_NODES + 1) * 4);
    int* bsum      = (int*)alloc(256 * 4);
    int* boff      = (int*)alloc(256 * 4);
    int* csr_src   = (int*)alloc(N_EDGES * 4);
    unsigned short* W0hi = (unsigned short*)alloc(512 * 512 * 2);
    unsigned short* W0lo = (unsigned short*)alloc(512 * 512 * 2);
    unsigned short* W1hi = (unsigned short*)alloc(512 * 512 * 2);
    unsigned short* W1lo = (unsigned short*)alloc(512 * 512 * 2);
    unsigned short* W2hi = (unsigned short*)alloc(256 * 512 * 2);
    unsigned short* W2lo = (unsigned short*)alloc(256 * 512 * 2);
    unsigned short* Ahi = (unsigned short*)alloc((size_t)N_NODES * 512 * 2);
    unsigned short* Alo = (unsigned short*)alloc((size_t)N_NODES * 512 * 2);
    unsigned short* H   = (unsigned short*)alloc((size_t)N_NODES * 512 * 2);

    const int NB = (N_NODES + 255) / 256;   // 196

    // ---- degrees + norms + CSR ----
    hipMemsetAsync(outc, 0, 3 * N_NODES * sizeof(int), stream);  // outc, inc, cursor contiguous
    hist_kernel<<<(N_EDGES + 255) / 256, 256, 0, stream>>>(src, dst, outc, inc);
    norm_kernel<<<(N_NODES + 255) / 256, 256, 0, stream>>>(outc, inc, outn, inn);
    scan1<<<NB, 256, 0, stream>>>(inc, row_start, bsum, N_NODES);
    scan2<<<1, 256, 0, stream>>>(bsum, boff, row_start, NB);
    scan3<<<NB, 256, 0, stream>>>(row_start, boff, N_NODES);
    fill_kernel<<<(N_EDGES + 255) / 256, 256, 0, stream>>>(src, dst, row_start, cursor, csr_src);

    // ---- weight transpose + split ----
    conv_W<<<dim3(16, 16), 256, 0, stream>>>(W0, W0hi, W0lo, 512, 512);
    conv_W<<<dim3(16, 16), 256, 0, stream>>>(W1, W1hi, W1lo, 512, 512);
    conv_W<<<dim3(16, 8),  256, 0, stream>>>(W2, W2hi, W2lo, 512, 256);

    // ---- feature scale + split ----
    long total4 = (long)N_NODES * 128;
    conv_A<<<(int)((total4 + 255) / 256), 256, 0, stream>>>(
        (const float4*)feat, outn, (ushort4*)Ahi, (ushort4*)Alo, total4);

    dim3 g512((N_NODES + 127) / 128, 4);
    dim3 g256((N_NODES + 127) / 128, 2);

    // ---- layer 0 ----
    gemm_mfma<<<g512, 256, 0, stream>>>(Ahi, Alo, W0hi, W0lo, H, N_NODES, 512);
    agg_bf16_512<<<N_NODES, 64, 0, stream>>>(
        H, csr_src, row_start, inn, outn, b0, (ushort8*)Ahi, (ushort8*)Alo);

    // ---- layer 1 ----
    gemm_mfma<<<g512, 256, 0, stream>>>(Ahi, Alo, W1hi, W1lo, H, N_NODES, 512);
    agg_bf16_512<<<N_NODES, 64, 0, stream>>>(
        H, csr_src, row_start, inn, outn, b1, (ushort8*)Ahi, (ushort8*)Alo);

    // ---- layer 2 (256 out, no relu, fp32) ----
    gemm_mfma<<<g256, 256, 0, stream>>>(Ahi, Alo, W2hi, W2lo, H, N_NODES, 256);
    agg_f32_256<<<N_NODES, 64, 0, stream>>>(
        H, csr_src, row_start, inn, b2, (float4*)out);
}

// Round 6
// 760.652 us; speedup vs baseline: 19.0965x; 1.2025x over previous
//
#include <hip/hip_runtime.h>

#define N_NODES 50000
#define N_EDGES 800000
// feats: 512 -> 512 -> 512 -> 256; K is always 512. Internal dtype: fp16.

typedef __attribute__((ext_vector_type(8))) _Float16 half8;
typedef __attribute__((ext_vector_type(4))) float f32x4;
typedef __attribute__((ext_vector_type(8))) unsigned short ushort8;

// ---------------- fp16 helpers ----------------
static __device__ __forceinline__ unsigned short f2h(float f) {
    _Float16 h = (_Float16)f;   // RNE
    return __builtin_bit_cast(unsigned short, h);
}
static __device__ __forceinline__ float h2f(unsigned short u) {
    return (float)__builtin_bit_cast(_Float16, u);
}

// async global->LDS, 16B per lane (wave-uniform LDS base + lane*16 layout)
static __device__ __forceinline__ void async16(unsigned short* lds, const unsigned short* g) {
    __builtin_amdgcn_global_load_lds(
        (const __attribute__((address_space(1))) void*)g,
        (__attribute__((address_space(3))) void*)lds, 16, 0, 0);
}

// ---------------- int degree histograms ----------------
__global__ void hist_kernel(const int* __restrict__ src, const int* __restrict__ dst,
                            int* __restrict__ outc, int* __restrict__ inc) {
    int i = blockIdx.x * blockDim.x + threadIdx.x;
    if (i < N_EDGES) {
        atomicAdd(&outc[src[i]], 1);
        atomicAdd(&inc[dst[i]], 1);
    }
}

__global__ void norm_kernel(const int* __restrict__ outc, const int* __restrict__ inc,
                            float* __restrict__ outn, float* __restrict__ inn) {
    int i = blockIdx.x * blockDim.x + threadIdx.x;
    if (i < N_NODES) {
        outn[i] = rsqrtf(fmaxf((float)outc[i], 1.0f));
        inn[i]  = rsqrtf(fmaxf((float)inc[i], 1.0f));
    }
}

// ---------------- hierarchical exclusive scan (3 kernels) ----------------
__global__ __launch_bounds__(256) void scan1(const int* __restrict__ cnt,
                                             int* __restrict__ row_start,
                                             int* __restrict__ bsum, int n) {
    __shared__ int t[256];
    int tid = threadIdx.x;
    int i = blockIdx.x * 256 + tid;
    int v = (i < n) ? cnt[i] : 0;
    t[tid] = v;
    __syncthreads();
#pragma unroll
    for (int off = 1; off < 256; off <<= 1) {
        int x = (tid >= off) ? t[tid - off] : 0;
        __syncthreads();
        t[tid] += x;
        __syncthreads();
    }
    if (i < n) row_start[i] = t[tid] - v;
    if (tid == 255) bsum[blockIdx.x] = t[255];
}

__global__ __launch_bounds__(256) void scan2(int* __restrict__ bsum,
                                             int* __restrict__ boff,
                                             int* __restrict__ row_start, int nb) {
    __shared__ int t[256];
    int tid = threadIdx.x;
    int v = (tid < nb) ? bsum[tid] : 0;
    t[tid] = v;
    __syncthreads();
#pragma unroll
    for (int off = 1; off < 256; off <<= 1) {
        int x = (tid >= off) ? t[tid - off] : 0;
        __syncthreads();
        t[tid] += x;
        __syncthreads();
    }
    if (tid < nb) boff[tid] = t[tid] - v;
    if (tid == 0) row_start[N_NODES] = N_EDGES;
}

__global__ __launch_bounds__(256) void scan3(int* __restrict__ row_start,
                                             const int* __restrict__ boff, int n) {
    int i = blockIdx.x * 256 + threadIdx.x;
    if (i < n) row_start[i] += boff[blockIdx.x];
}

// ---------------- CSR fill ----------------
__global__ void fill_kernel(const int* __restrict__ src, const int* __restrict__ dst,
                            const int* __restrict__ row_start, int* __restrict__ cursor,
                            int* __restrict__ csr_src) {
    int e = blockIdx.x * blockDim.x + threadIdx.x;
    if (e < N_EDGES) {
        int d = dst[e];
        int pos = atomicAdd(&cursor[d], 1);
        csr_src[row_start[d] + pos] = src[e];
    }
}

// ---------------- W [K,N] fp32 -> Wt [N,K] fp16 (transpose) ----------------
__global__ __launch_bounds__(256) void conv_W(const float* __restrict__ W,
                                              unsigned short* __restrict__ Wt,
                                              int K, int N) {
    __shared__ float t[32][33];
    int tx = threadIdx.x & 31, ty = threadIdx.x >> 5;   // 32 x 8
    int kb = blockIdx.x * 32, nb = blockIdx.y * 32;
#pragma unroll
    for (int i = 0; i < 4; ++i)
        t[ty + 8 * i][tx] = W[(size_t)(kb + ty + 8 * i) * N + nb + tx];
    __syncthreads();
#pragma unroll
    for (int i = 0; i < 4; ++i) {
        float v = t[tx][ty + 8 * i];
        int n = nb + ty + 8 * i, k = kb + tx;
        Wt[(size_t)n * K + k] = f2h(v);
    }
}

// ---------------- feat [M,512] fp32 -> (outn[row]*feat) fp16 ----------------
__global__ void conv_A(const float4* __restrict__ feat4, const float* __restrict__ outn,
                       ushort4* __restrict__ Af, long total4) {
    long i = (long)blockIdx.x * blockDim.x + threadIdx.x;
    if (i >= total4) return;
    int row = (int)(i >> 7);            // 512/4 = 128 float4 per row
    float s = outn[row];
    float4 v = feat4[i];
    ushort4 h;
    h.x = f2h(v.x * s);
    h.y = f2h(v.y * s);
    h.z = f2h(v.z * s);
    h.w = f2h(v.w * s);
    Af[i] = h;
}

// ---------------- MFMA GEMM: C[M,N] = A @ B^T, fp16 in/out, fp32 acc, K=512 ----------------
// 128x128 tile, BK=32, 256 threads = 4 waves; global_load_lds (16B) staging.
__global__ __launch_bounds__(256) void gemm_mfma(
    const unsigned short* __restrict__ A, const unsigned short* __restrict__ B,
    unsigned short* __restrict__ C, int M, int N)
{
    const int K = 512;
    __shared__ unsigned short sA[128 * 32];
    __shared__ unsigned short sB[128 * 32];

    const int tid = threadIdx.x;
    const int rowBase = blockIdx.x * 128;
    const int colBase = blockIdx.y * 128;
    const int wave = tid >> 6;
    const int lane = tid & 63;
    const int wr = (wave >> 1) * 64;
    const int wc = (wave & 1) * 64;
    const int lrow = lane & 15;
    const int quad = lane >> 4;

    f32x4 acc[4][4] = {};

    // staging: thread tid -> row tid>>2 (and +64), k-chunk (tid&3)*8; LDS dest = tid*16 B
    const int crow = tid >> 2;
    const int ck   = (tid & 3) * 8;
    const int ar0 = min(rowBase + crow, M - 1);
    const int ar1 = min(rowBase + 64 + crow, M - 1);
    const int bn0 = colBase + crow;
    const int bn1 = colBase + 64 + crow;
    const int ldsOf0 = tid * 8;          // ushort units
    const int ldsOf1 = 64 * 32 + tid * 8;

    for (int k0 = 0; k0 < K; k0 += 32) {
        __syncthreads();   // previous tile's compute done before overwrite
        async16(sA + ldsOf0, A + (size_t)ar0 * K + k0 + ck);
        async16(sA + ldsOf1, A + (size_t)ar1 * K + k0 + ck);
        async16(sB + ldsOf0, B + (size_t)bn0 * K + k0 + ck);
        async16(sB + ldsOf1, B + (size_t)bn1 * K + k0 + ck);
        __syncthreads();   // drains vmcnt (global_load_lds) + barrier

        half8 av[4], bv[4];
#pragma unroll
        for (int mt = 0; mt < 4; ++mt)
            av[mt] = *(const half8*)&sA[(wr + mt * 16 + lrow) * 32 + quad * 8];
#pragma unroll
        for (int nt = 0; nt < 4; ++nt)
            bv[nt] = *(const half8*)&sB[(wc + nt * 16 + lrow) * 32 + quad * 8];
#pragma unroll
        for (int mt = 0; mt < 4; ++mt)
#pragma unroll
            for (int nt = 0; nt < 4; ++nt)
                acc[mt][nt] = __builtin_amdgcn_mfma_f32_16x16x32_f16(av[mt], bv[nt], acc[mt][nt], 0, 0, 0);
    }

    // epilogue: C/D layout col=lane&15, row=quad*4+reg; store fp16
#pragma unroll
    for (int mt = 0; mt < 4; ++mt) {
        int grow0 = rowBase + wr + mt * 16 + quad * 4;
#pragma unroll
        for (int nt = 0; nt < 4; ++nt) {
            int gcol = colBase + wc + nt * 16 + lrow;
#pragma unroll
            for (int r = 0; r < 4; ++r) {
                int grow = grow0 + r;
                if (grow < M) C[(size_t)grow * N + gcol] = f2h(acc[mt][nt][r]);
            }
        }
    }
}

// ---------------- gather-aggregate (fp16 H, 512 feats) -> fp16 A (next layer) ----------------
// 64 threads, 8 feats (16B) per lane; fp32 accumulate; norm+bias+relu+outn fused.
__global__ __launch_bounds__(64) void agg_f16_512(
    const unsigned short* __restrict__ H, const int* __restrict__ csr_src,
    const int* __restrict__ row_start, const float* __restrict__ inn,
    const float* __restrict__ outn, const float* __restrict__ bias,
    ushort8* __restrict__ Af)
{
    const int d = blockIdx.x;
    const int tid = threadIdx.x;
    const int start = row_start[d];
    const int end   = row_start[d + 1];
    const unsigned short* Hb = H + tid * 8;

    float acc[8] = {};
    int j = start;
    for (; j + 4 <= end; j += 4) {
        int i0 = csr_src[j + 0], i1 = csr_src[j + 1];
        int i2 = csr_src[j + 2], i3 = csr_src[j + 3];
        ushort8 u0 = *(const ushort8*)(Hb + (size_t)i0 * 512);
        ushort8 u1 = *(const ushort8*)(Hb + (size_t)i1 * 512);
        ushort8 u2 = *(const ushort8*)(Hb + (size_t)i2 * 512);
        ushort8 u3 = *(const ushort8*)(Hb + (size_t)i3 * 512);
#pragma unroll
        for (int q = 0; q < 8; ++q) {
            acc[q] += h2f(u0[q]);
            acc[q] += h2f(u1[q]);
            acc[q] += h2f(u2[q]);
            acc[q] += h2f(u3[q]);
        }
    }
    for (; j < end; ++j) {
        int i0 = csr_src[j];
        ushort8 u0 = *(const ushort8*)(Hb + (size_t)i0 * 512);
#pragma unroll
        for (int q = 0; q < 8; ++q) acc[q] += h2f(u0[q]);
    }

    float s = inn[d];
    float so = outn[d];
    float b[8];
    *(float4*)&b[0] = ((const float4*)bias)[tid * 2 + 0];
    *(float4*)&b[4] = ((const float4*)bias)[tid * 2 + 1];
    ushort8 h;
#pragma unroll
    for (int q = 0; q < 8; ++q)
        h[q] = f2h(fmaxf(acc[q] * s + b[q], 0.f) * so);
    Af[(size_t)d * 64 + tid] = h;
}

// ---------------- final aggregate (fp16 H, 256 feats) -> fp32 out, no relu ----------------
__global__ __launch_bounds__(64) void agg_f32_256(
    const unsigned short* __restrict__ H, const int* __restrict__ csr_src,
    const int* __restrict__ row_start, const float* __restrict__ inn,
    const float* __restrict__ bias, float4* __restrict__ out)
{
    const int d = blockIdx.x;
    const int tid = threadIdx.x;
    const int start = row_start[d];
    const int end   = row_start[d + 1];
    const unsigned short* Hb = H + tid * 4;

    float acc[4] = {};
    int j = start;
    for (; j + 4 <= end; j += 4) {
        int i0 = csr_src[j + 0], i1 = csr_src[j + 1];
        int i2 = csr_src[j + 2], i3 = csr_src[j + 3];
        ushort4 u0 = *(const ushort4*)(Hb + (size_t)i0 * 256);
        ushort4 u1 = *(const ushort4*)(Hb + (size_t)i1 * 256);
        ushort4 u2 = *(const ushort4*)(Hb + (size_t)i2 * 256);
        ushort4 u3 = *(const ushort4*)(Hb + (size_t)i3 * 256);
        acc[0] += h2f(u0.x) + h2f(u1.x) + h2f(u2.x) + h2f(u3.x);
        acc[1] += h2f(u0.y) + h2f(u1.y) + h2f(u2.y) + h2f(u3.y);
        acc[2] += h2f(u0.z) + h2f(u1.z) + h2f(u2.z) + h2f(u3.z);
        acc[3] += h2f(u0.w) + h2f(u1.w) + h2f(u2.w) + h2f(u3.w);
    }
    for (; j < end; ++j) {
        ushort4 u0 = *(const ushort4*)(Hb + (size_t)csr_src[j] * 256);
        acc[0] += h2f(u0.x); acc[1] += h2f(u0.y);
        acc[2] += h2f(u0.z); acc[3] += h2f(u0.w);
    }

    float s = inn[d];
    float4 b = ((const float4*)bias)[tid];
    float4 r;
    r.x = acc[0] * s + b.x;
    r.y = acc[1] * s + b.y;
    r.z = acc[2] * s + b.z;
    r.w = acc[3] * s + b.w;
    out[(size_t)d * 64 + tid] = r;
}

extern "C" void kernel_launch(void* const* d_in, const int* in_sizes, int n_in,
                              void* d_out, int out_size, void* d_ws, size_t ws_size,
                              hipStream_t stream) {
    const float* feat = (const float*)d_in[0];
    const int*   src  = (const int*)d_in[1];
    const int*   dst  = (const int*)d_in[2];
    const float* W0   = (const float*)d_in[3];
    const float* b0   = (const float*)d_in[4];
    const float* W1   = (const float*)d_in[5];
    const float* b1   = (const float*)d_in[6];
    const float* W2   = (const float*)d_in[7];
    const float* b2   = (const float*)d_in[8];
    float* out = (float*)d_out;

    // ---- workspace bump allocator (64B aligned) ----
    char* p = (char*)d_ws;
    auto alloc = [&](size_t bytes) {
        char* r = p;
        p += (bytes + 63) & ~(size_t)63;
        return r;
    };
    float* outn = (float*)alloc(N_NODES * 4);
    float* inn  = (float*)alloc(N_NODES * 4);
    int* outc      = (int*)alloc(N_NODES * 4);
    int* inc       = (int*)alloc(N_NODES * 4);
    int* cursor    = (int*)alloc(N_NODES * 4);
    int* row_start = (int*)alloc((N_NODES + 1) * 4);
    int* bsum      = (int*)alloc(256 * 4);
    int* boff      = (int*)alloc(256 * 4);
    int* csr_src   = (int*)alloc(N_EDGES * 4);
    unsigned short* W0t = (unsigned short*)alloc(512 * 512 * 2);
    unsigned short* W1t = (unsigned short*)alloc(512 * 512 * 2);
    unsigned short* W2t = (unsigned short*)alloc(256 * 512 * 2);
    unsigned short* Af  = (unsigned short*)alloc((size_t)N_NODES * 512 * 2);
    unsigned short* H   = (unsigned short*)alloc((size_t)N_NODES * 512 * 2);

    const int NB = (N_NODES + 255) / 256;   // 196

    // ---- degrees + norms + CSR ----
    hipMemsetAsync(outc, 0, 3 * N_NODES * sizeof(int), stream);  // outc, inc, cursor contiguous
    hist_kernel<<<(N_EDGES + 255) / 256, 256, 0, stream>>>(src, dst, outc, inc);
    norm_kernel<<<(N_NODES + 255) / 256, 256, 0, stream>>>(outc, inc, outn, inn);
    scan1<<<NB, 256, 0, stream>>>(inc, row_start, bsum, N_NODES);
    scan2<<<1, 256, 0, stream>>>(bsum, boff, row_start, NB);
    scan3<<<NB, 256, 0, stream>>>(row_start, boff, N_NODES);
    fill_kernel<<<(N_EDGES + 255) / 256, 256, 0, stream>>>(src, dst, row_start, cursor, csr_src);

    // ---- weight transpose to fp16 ----
    conv_W<<<dim3(16, 16), 256, 0, stream>>>(W0, W0t, 512, 512);
    conv_W<<<dim3(16, 16), 256, 0, stream>>>(W1, W1t, 512, 512);
    conv_W<<<dim3(16, 8),  256, 0, stream>>>(W2, W2t, 512, 256);

    // ---- feature scale to fp16 ----
    long total4 = (long)N_NODES * 128;
    conv_A<<<(int)((total4 + 255) / 256), 256, 0, stream>>>(
        (const float4*)feat, outn, (ushort4*)Af, total4);

    dim3 g512((N_NODES + 127) / 128, 4);
    dim3 g256((N_NODES + 127) / 128, 2);

    // ---- layer 0 ----
    gemm_mfma<<<g512, 256, 0, stream>>>(Af, W0t, H, N_NODES, 512);
    agg_f16_512<<<N_NODES, 64, 0, stream>>>(
        H, csr_src, row_start, inn, outn, b0, (ushort8*)Af);

    // ---- layer 1 ----
    gemm_mfma<<<g512, 256, 0, stream>>>(Af, W1t, H, N_NODES, 512);
    agg_f16_512<<<N_NODES, 64, 0, stream>>>(
        H, csr_src, row_start, inn, outn, b1, (ushort8*)Af);

    // ---- layer 2 (256 out, no relu, fp32) ----
    gemm_mfma<<<g256, 256, 0, stream>>>(Af, W2t, H, N_NODES, 256);
    agg_f32_256<<<N_NODES, 64, 0, stream>>>(
        H, csr_src, row_start, inn, b2, (float4*)out);
}